// Round 5
// baseline (877.742 us; speedup 1.0000x reference)
//
#include <hip/hip_runtime.h>
#include <math.h>

typedef __attribute__((ext_vector_type(4))) float f32x4;
typedef __attribute__((ext_vector_type(8))) short bf16x8;
typedef __attribute__((ext_vector_type(4))) unsigned short u16x4;

__device__ __forceinline__ unsigned short f2bf(float f) {
  unsigned u = __builtin_bit_cast(unsigned, f);
  u += 0x7fffu + ((u >> 16) & 1u);
  return (unsigned short)(u >> 16);
}
__device__ __forceinline__ float bf2f(unsigned short s) {
  return __builtin_bit_cast(float, (unsigned)s << 16);
}
__device__ __forceinline__ float sigmoidf_(float x) { return 1.f / (1.f + __expf(-x)); }

// ---------------------------------------------------------------------------
// bf16-MFMA GEMM, 128xTN tile (TN=128 or 64), BK=32, 4 waves, double-buffered
// LDS + 1-deep register prefetch, bijective XCD swizzle (grid product %8==0).
// C[M,N] = A[M,K] @ B[N,K]^T (+bias).
// ACAT/BCAT: K-concat (1st ptr k<Ksplit, 2nd after). z-split: z>=zs -> "b" set.
// ABF16: A is bf16. OBF16: C bf16 (EPI 0/3).
// EPI 0: (val)*scale
// EPI 1: val + P0[off] + P1[off]
// EPI 2: (P2+P3+ce+sig(val)*(P1-ce))/3, ce=P0[row*256+(col&255)]
// EPI 3: val * P0[2*row+hi]                       (rw-scaled, bf16 out)
// EPI 4: val + P2[2*row]*P0[col] + P2[2*row+1]*P1[col]
// ---------------------------------------------------------------------------
template <int TN, int ACAT, int BCAT, int EPI, int ABF16, int OBF16>
__global__ __launch_bounds__(256) void gemm_k(
    const void* __restrict__ A1, const void* __restrict__ A1b, int lda1, long aZ,
    const void* __restrict__ A2, int lda2, int Ksplit,
    const float* __restrict__ B1, const float* __restrict__ B1b, int ldb1, long bZ,
    const float* __restrict__ B2, int ldb2,
    const float* __restrict__ bias1, const float* __restrict__ bias1b, long biasZ,
    const float* __restrict__ bias2,
    void* __restrict__ C, void* __restrict__ Cb, int ldc, long cZ,
    int K, int zs, float scale,
    const float* __restrict__ P0, const float* __restrict__ P1,
    const float* __restrict__ P2, const float* __restrict__ P3) {
  constexpr int NBI = TN / 32;
  __shared__ unsigned short As[2][128][32];
  __shared__ unsigned short Bs[2][TN][32];
  const int t = threadIdx.x;
  const int lane = t & 63;
  const int wave = t >> 6;
  const int wr = wave >> 1, wc = wave & 1;

  const unsigned gx = gridDim.x, gy = gridDim.y;
  unsigned L = blockIdx.x + gx * (blockIdx.y + gy * blockIdx.z);
  const unsigned nwg = gx * gy * gridDim.z;
  L = (L & 7u) * (nwg >> 3) + (L >> 3);
  const int bn = L % gx;
  const unsigned r1 = L / gx;
  const int bm = r1 % gy;
  const int z = r1 / gy;

  const bool hi = z >= zs;
  const int zz = hi ? z - zs : z;
  const char* Abase = (const char*)(hi ? A1b : A1) + (long)zz * aZ * (ABF16 ? 2 : 4);
  const float* Bbase = (hi ? B1b : B1) + (long)zz * bZ;
  const float* biasp = hi ? bias1b : bias1;
  char* Czc = (char*)(hi ? Cb : C) + (long)zz * cZ * (OBF16 ? 2 : 4);

  const int ar = t >> 3;
  const int bc = (t & 7) * 4;

  const int kIters = K >> 5;
  u16x4 Ra[4], Rb[NBI];

  auto loadT = [&](int kt) {
    const int k0 = kt << 5;
    const char* Ap; int ldA, kA;
    if (ACAT == 1 && k0 >= Ksplit) { Ap = (const char*)A2; ldA = lda2; kA = k0 - Ksplit; }
    else { Ap = Abase; ldA = lda1; kA = k0; }
    const float* Bp; int ldB, kB;
    if (BCAT == 1 && k0 >= Ksplit) { Bp = B2; ldB = ldb2; kB = k0 - Ksplit; }
    else { Bp = Bbase; ldB = ldb1; kB = k0; }
#pragma unroll
    for (int i = 0; i < 4; ++i) {
      const long aoff = ((long)bm * 128 + ar + 32 * i) * ldA + kA + bc;
      if (ABF16) {
        Ra[i] = *(const u16x4*)((const unsigned short*)Ap + aoff);
      } else {
        f32x4 v = *(const f32x4*)((const float*)Ap + aoff);
        u16x4 pk;
        pk[0] = f2bf(v[0]); pk[1] = f2bf(v[1]); pk[2] = f2bf(v[2]); pk[3] = f2bf(v[3]);
        Ra[i] = pk;
      }
    }
#pragma unroll
    for (int i = 0; i < NBI; ++i) {
      f32x4 bv = *(const f32x4*)(Bp + ((long)bn * TN + ar + 32 * i) * ldB + kB + bc);
      u16x4 bp;
      bp[0] = f2bf(bv[0]); bp[1] = f2bf(bv[1]); bp[2] = f2bf(bv[2]); bp[3] = f2bf(bv[3]);
      Rb[i] = bp;
    }
  };

  loadT(0);

  f32x4 acc[4][NBI] = {};
  int p = 0;
  for (int kt = 0; kt < kIters; ++kt) {
    __syncthreads();
#pragma unroll
    for (int i = 0; i < 4; ++i) *(u16x4*)&As[p][ar + 32 * i][bc] = Ra[i];
#pragma unroll
    for (int i = 0; i < NBI; ++i) *(u16x4*)&Bs[p][ar + 32 * i][bc] = Rb[i];
    if (kt + 1 < kIters) loadT(kt + 1);
    __syncthreads();

    bf16x8 af[4], bfr[NBI];
#pragma unroll
    for (int mi = 0; mi < 4; ++mi)
      af[mi] = *(const bf16x8*)&As[p][wr * 64 + mi * 16 + (lane & 15)][(lane >> 4) * 8];
#pragma unroll
    for (int ni = 0; ni < NBI; ++ni)
      bfr[ni] = *(const bf16x8*)&Bs[p][wc * (TN / 2) + ni * 16 + (lane & 15)][(lane >> 4) * 8];
#pragma unroll
    for (int mi = 0; mi < 4; ++mi)
#pragma unroll
      for (int ni = 0; ni < NBI; ++ni)
        acc[mi][ni] = __builtin_amdgcn_mfma_f32_16x16x32_bf16(af[mi], bfr[ni], acc[mi][ni], 0, 0, 0);
    p ^= 1;
  }

  const int colb = bn * TN + wc * (TN / 2);
  const int rowb = bm * 128 + wr * 64;
#pragma unroll
  for (int mi = 0; mi < 4; ++mi) {
#pragma unroll
    for (int ni = 0; ni < NBI; ++ni) {
      f32x4 v = acc[mi][ni];
      const int col = colb + ni * 16 + (lane & 15);
      const int row0 = rowb + mi * 16 + ((lane >> 4) << 2);
      float bsum = 0.f;
      if (biasp) bsum += biasp[zz * biasZ + col];
      if (bias2) bsum += bias2[col];
#pragma unroll
      for (int q = 0; q < 4; ++q) {
        const long row = row0 + q;
        const long off = row * ldc + col;
        const float val = v[q] + bsum;
        if (EPI == 0) {
          if (OBF16) ((unsigned short*)Czc)[off] = f2bf(val * scale);
          else       ((float*)Czc)[off] = val * scale;
        } else if (EPI == 1) {
          ((float*)Czc)[off] = val + P0[off] + P1[off];
        } else if (EPI == 2) {
          const float g = sigmoidf_(val);
          const float ce = P0[row * 256 + (col & 255)];
          const float ex = P1[off];
          ((float*)Czc)[off] = (P2[off] + P3[off] + ce + g * (ex - ce)) * (1.f / 3.f);
        } else if (EPI == 3) {
          ((unsigned short*)Czc)[off] = f2bf(val * P0[2 * row + (hi ? 1 : 0)]);
        } else {
          ((float*)Czc)[off] = val + P2[2 * row] * P0[col] + P2[2 * row + 1] * P1[col];
        }
      }
    }
  }
}

// 64x64 LDS-tiled transpose, z selects (in,out) pair. out[n][d] = in[d][n]
__global__ __launch_bounds__(256) void transpose_k(const float* __restrict__ in0,
                                                   float* __restrict__ out0,
                                                   const float* __restrict__ in1,
                                                   float* __restrict__ out1, int n) {
  __shared__ float tile[64][65];
  const float* in = blockIdx.z ? in1 : in0;
  float* out = blockIdx.z ? out1 : out0;
  const int tr = blockIdx.y, tc = blockIdx.x, t = threadIdx.x;
#pragma unroll
  for (int it = 0; it < 16; ++it) {
    int idx = t + 256 * it;
    int r = idx >> 6, c = idx & 63;
    tile[r][c] = in[(long)(tr * 64 + r) * n + tc * 64 + c];
  }
  __syncthreads();
#pragma unroll
  for (int it = 0; it < 16; ++it) {
    int idx = t + 256 * it;
    int rr = idx >> 6, cc = idx & 63;
    out[(long)(tc * 64 + rr) * n + tr * 64 + cc] = tile[cc][rr];
  }
}

// LSTM elementwise + fused router (block == one batch row b)
__global__ __launch_bounds__(256) void lstm_k(const float* __restrict__ gates,
                                              const float* __restrict__ c_in,
                                              const float* __restrict__ Wr,
                                              const float* __restrict__ br,
                                              float* __restrict__ c_out,
                                              float* __restrict__ h_ws,
                                              float* __restrict__ h_out,
                                              float* __restrict__ rw) {
  const int b = blockIdx.x, t = threadIdx.x;
  const long base = (long)b * 1024 + t * 4;
  const float* gb = gates + (long)b * 4096 + t * 4;
  f32x4 gi = *(const f32x4*)(gb);
  f32x4 gf = *(const f32x4*)(gb + 1024);
  f32x4 gg = *(const f32x4*)(gb + 2048);
  f32x4 go = *(const f32x4*)(gb + 3072);
  f32x4 cv = *(const f32x4*)(c_in + base);
  f32x4 cn, hv;
#pragma unroll
  for (int q = 0; q < 4; ++q) {
    float cc = sigmoidf_(gf[q]) * cv[q] + sigmoidf_(gi[q]) * tanhf(gg[q]);
    cn[q] = cc;
    hv[q] = sigmoidf_(go[q]) * tanhf(cc);
  }
  *(f32x4*)(c_out + base) = cn;
  *(f32x4*)(h_ws + base) = hv;
  *(f32x4*)(h_out + base) = hv;
  f32x4 w0 = *(const f32x4*)(Wr + t * 4);
  f32x4 w1 = *(const f32x4*)(Wr + 1024 + t * 4);
  float a0 = hv[0] * w0[0] + hv[1] * w0[1] + hv[2] * w0[2] + hv[3] * w0[3];
  float a1 = hv[0] * w1[0] + hv[1] * w1[1] + hv[2] * w1[2] + hv[3] * w1[3];
#pragma unroll
  for (int m = 32; m >= 1; m >>= 1) {
    a0 += __shfl_xor(a0, m);
    a1 += __shfl_xor(a1, m);
  }
  __shared__ float red[8];
  if ((t & 63) == 0) { red[t >> 6] = a0; red[4 + (t >> 6)] = a1; }
  __syncthreads();
  if (t == 0) {
    float z0 = red[0] + red[1] + red[2] + red[3] + br[0];
    float z1 = red[4] + red[5] + red[6] + red[7] + br[1];
    float mx = fmaxf(z0, z1);
    float e0 = __expf(z0 - mx), e1 = __expf(z1 - mx);
    float s = e0 + e1;
    rw[2 * b] = e0 / s;
    rw[2 * b + 1] = e1 / s;
  }
}

// ---------------------------------------------------------------------------
// Attention stage 1: partial scores. Block (b, side, ch): stage K chunk
// [32l x 128k] as bf16 in MFMA-A layout, 2 MFMAs vs qt chunk, cross-wave
// reduce, write pS[(b,side),ch,h*32+l]. Self side also writes ts chunk.
// ---------------------------------------------------------------------------
__global__ __launch_bounds__(256) void scores_k(
    const float* __restrict__ memK, const float* __restrict__ extK,
    const float* __restrict__ hl,
    const unsigned short* __restrict__ qtS, const unsigned short* __restrict__ qtE,
    float* __restrict__ pS, float* __restrict__ ts) {
  const int NB = 2048, H = 1024;
  __shared__ __align__(16) unsigned short KT[4 * 1168];  // [j]:1168, row pitch 36
  __shared__ float Sp[4][32][17];
  const int b = blockIdx.x, side = blockIdx.y, ch = blockIdx.z;
  const bool self = side == 0;
  const int t = threadIdx.x, lane = t & 63, w = t >> 6;

#pragma unroll
  for (int it = 0; it < 4; ++it) {
    int f = t + 256 * it;
    int r = f >> 5, c4 = f & 31;
    const float* src = self ? ((r < 31) ? memK + ((long)(r + 1) * NB + b) * H : hl + (long)b * H)
                            : extK + ((long)r * NB + b) * H;
    f32x4 v = *(const f32x4*)(src + ch * 128 + c4 * 4);
    *(u16x4*)&KT[(c4 >> 3) * 1168 + r * 36 + (c4 & 7) * 4] =
        (u16x4){f2bf(v[0]), f2bf(v[1]), f2bf(v[2]), f2bf(v[3])};
  }
  __syncthreads();
  if (self && t < 128) {
    float s = 0.f;
    const unsigned short* kc = KT + (t >> 5) * 1168 + (t & 31);
#pragma unroll
    for (int lr = 0; lr < 32; ++lr) s += bf2f(kc[lr * 36]);
    ts[(long)b * H + ch * 128 + t] = s * (1.f / 32.f);
  }
  const unsigned short* qt =
      (self ? qtS : qtE) + (long)b * 8192 + (lane & 7) * 1024 + ch * 128;
  bf16x8 bq = *(const bf16x8*)(qt + w * 32 + (lane >> 4) * 8);
  f32x4 accS[2] = {};
#pragma unroll
  for (int mi = 0; mi < 2; ++mi) {
    const unsigned short* ap = &KT[w * 1168 + (mi * 16 + (lane & 15)) * 36 + (lane >> 4) * 8];
    union { unsigned long long q[2]; bf16x8 v; } ua;
    ua.q[0] = *(const unsigned long long*)ap;
    ua.q[1] = *(const unsigned long long*)(ap + 4);
    accS[mi] = __builtin_amdgcn_mfma_f32_16x16x32_bf16(ua.v, bq, accS[mi], 0, 0, 0);
  }
#pragma unroll
  for (int mi = 0; mi < 2; ++mi)
#pragma unroll
    for (int q = 0; q < 4; ++q)
      Sp[w][mi * 16 + (lane >> 4) * 4 + q][lane & 15] = accS[mi][q];
  __syncthreads();
  const int l = t & 31, head = t >> 5;
  float S = Sp[0][l][head] + Sp[1][l][head] + Sp[2][l][head] + Sp[3][l][head];
  pS[(((long)b * 2 + side) * 8 + ch) * 256 + t] = S;
}

// ---------------------------------------------------------------------------
// Attention stage 2: softmax. Block (b,side): sum 8 partials, softmax over l
// per head, write P bf16 [16 x 32] (rows 8..15 zero) in MFMA-A layout.
// ---------------------------------------------------------------------------
__global__ __launch_bounds__(256) void softmax_k(const float* __restrict__ pS,
                                                 unsigned short* __restrict__ Pbuf) {
  const long bs = (long)blockIdx.x * 2 + blockIdx.y;
  const int t = threadIdx.x;
  const float* base = pS + bs * 8 * 256;
  float S = 0.f;
#pragma unroll
  for (int ch = 0; ch < 8; ++ch) S += base[ch * 256 + t];
  float mx = S;
#pragma unroll
  for (int m = 16; m >= 1; m >>= 1) mx = fmaxf(mx, __shfl_xor(mx, m, 32));
  float pr = __expf(S - mx);
  float sum = pr;
#pragma unroll
  for (int m = 16; m >= 1; m >>= 1) sum += __shfl_xor(sum, m, 32);
  pr /= sum;
  unsigned short* Pb = Pbuf + bs * 512;
  Pb[t] = f2bf(pr);
  Pb[256 + t] = 0;
}

// ---------------------------------------------------------------------------
// Attention stage 3: V mix. Block (b, side, ch): stage V chunk transposed
// [128d x 32l] bf16, P from global as A-frag, 2 MFMAs per wave, write mix
// chunk bf16.
// ---------------------------------------------------------------------------
__global__ __launch_bounds__(256) void mix_k(
    const float* __restrict__ memV, const float* __restrict__ extV,
    const float* __restrict__ hl,
    const unsigned short* __restrict__ Pbuf,
    unsigned short* __restrict__ mixS, unsigned short* __restrict__ mixE) {
  const int NB = 2048, H = 1024;
  __shared__ __align__(16) unsigned short Vt[128][36];
  const int b = blockIdx.x, side = blockIdx.y, ch = blockIdx.z;
  const bool self = side == 0;
  const int t = threadIdx.x, lane = t & 63, w = t >> 6;
  const int l2 = t & 15, dgrp = t >> 4;

  const float* baseV0;
  const float* baseV1;
  {
    int r0 = 2 * l2, r1v = 2 * l2 + 1;
    if (self) {
      baseV0 = memV + ((long)(r0 + 1) * NB + b) * H;
      baseV1 = (r1v < 31) ? (memV + ((long)(r1v + 1) * NB + b) * H) : (hl + (long)b * H);
    } else {
      baseV0 = extV + ((long)r0 * NB + b) * H;
      baseV1 = extV + ((long)r1v * NB + b) * H;
    }
  }
  f32x4 R0 = *(const f32x4*)(baseV0 + ch * 128 + dgrp * 8);
  f32x4 R1 = *(const f32x4*)(baseV0 + ch * 128 + dgrp * 8 + 4);
  f32x4 R2 = *(const f32x4*)(baseV1 + ch * 128 + dgrp * 8);
  f32x4 R3 = *(const f32x4*)(baseV1 + ch * 128 + dgrp * 8 + 4);
  bf16x8 pa = *(const bf16x8*)(Pbuf + ((long)b * 2 + side) * 512 + (lane & 15) * 32 +
                               (lane >> 4) * 8);
#pragma unroll
  for (int e = 0; e < 4; ++e) {
    unsigned lo0 = (unsigned)f2bf(R0[e]) | ((unsigned)f2bf(R2[e]) << 16);
    unsigned lo1 = (unsigned)f2bf(R1[e]) | ((unsigned)f2bf(R3[e]) << 16);
    *(unsigned*)&Vt[dgrp * 8 + e][2 * l2] = lo0;
    *(unsigned*)&Vt[dgrp * 8 + 4 + e][2 * l2] = lo1;
  }
  __syncthreads();
  unsigned short* mixp = (self ? mixS : mixE) + (long)b * 8192;
#pragma unroll
  for (int i = 0; i < 2; ++i) {
    const int dbase = w * 32 + i * 16;
    const unsigned short* vb = &Vt[dbase + (lane & 15)][(lane >> 4) * 8];
    union { unsigned long long q[2]; bf16x8 v; } uu;
    uu.q[0] = *(const unsigned long long*)vb;
    uu.q[1] = *(const unsigned long long*)(vb + 4);
    f32x4 o = __builtin_amdgcn_mfma_f32_16x16x32_bf16(pa, uu.v, (f32x4){0.f, 0.f, 0.f, 0.f},
                                                      0, 0, 0);
    if (lane < 32) {
      const int d = ch * 128 + dbase + (lane & 15);
      const int h0 = (lane >> 4) * 4;
#pragma unroll
      for (int q = 0; q < 4; ++q) mixp[(long)(h0 + q) * 1024 + d] = f2bf(o[q]);
    }
  }
}

extern "C" void kernel_launch(void* const* d_in, const int* in_sizes, int n_in,
                              void* d_out, int out_size, void* d_ws, size_t ws_size,
                              hipStream_t stream) {
  const float* x    = (const float*)d_in[0];
  const float* h    = (const float*)d_in[1];
  const float* c    = (const float*)d_in[2];
  const float* memK = (const float*)d_in[3];
  const float* memV = (const float*)d_in[4];
  const float* extK = (const float*)d_in[5];
  const float* extV = (const float*)d_in[6];
  const float* W_ih = (const float*)d_in[7];
  const float* W_hh = (const float*)d_in[8];
  const float* b_ih = (const float*)d_in[9];
  const float* b_hh = (const float*)d_in[10];
  const float* sWq = (const float*)d_in[11];
  const float* sbq = (const float*)d_in[12];
  const float* sWk = (const float*)d_in[13];
  const float* sWv = (const float*)d_in[15];
  const float* sbv = (const float*)d_in[16];
  const float* sWo = (const float*)d_in[17];
  const float* sbo = (const float*)d_in[18];
  const float* cWq = (const float*)d_in[19];
  const float* cbq = (const float*)d_in[20];
  const float* cWk = (const float*)d_in[21];
  const float* cWv = (const float*)d_in[23];
  const float* cbv = (const float*)d_in[24];
  const float* cWo = (const float*)d_in[25];
  const float* cbo = (const float*)d_in[26];
  const float* Wres = (const float*)d_in[27];
  const float* bres = (const float*)d_in[28];
  const float* Wrout = (const float*)d_in[29];
  const float* brout = (const float*)d_in[30];
  const float* Wcomp = (const float*)d_in[31];
  const float* bcomp = (const float*)d_in[32];
  const float* Wexp = (const float*)d_in[33];
  const float* bexp = (const float*)d_in[34];
  const float* Wgate = (const float*)d_in[35];
  const float* bgate = (const float*)d_in[36];
  (void)in_sizes; (void)n_in; (void)out_size; (void)ws_size;

  float* out = (float*)d_out;
  float* w = (float*)d_ws;
  const long M1 = 1024 * 1024;
  float* gates   = w;            // [2048,4096] f32 ; dead after lstm_k
  float* pS      = w;            // [2048,2,8,256] f32 (32MB) reuses gates
  float* hl      = w + 8 * M1;   // [2048,1024] f32
  unsigned short* qsS = (unsigned short*)(w + 10 * M1);  // [2048,1024] bf16; dead after qt
  unsigned short* Pbuf = (unsigned short*)(w + 10 * M1); // [2048,2,512] bf16 reuses qsS
  unsigned short* qsE = (unsigned short*)(w + 12 * M1);
  float* wkTs    = w + 14 * M1;  // [1024,1024] f32
  float* wkTc    = w + 15 * M1;
  unsigned short* qtS = (unsigned short*)(w + 16 * M1);  // [2048,8192] bf16
  unsigned short* qtE = (unsigned short*)(w + 32 * M1);
  unsigned short* mixS = (unsigned short*)(w + 48 * M1); // [2048,8192] bf16
  unsigned short* mixE = (unsigned short*)(w + 64 * M1);
  float* ts      = w + 80 * M1;  // [2048,1024] f32
  unsigned short* attnS = (unsigned short*)(w + 82 * M1);  // [2048,1024] bf16 (rw-scaled)
  unsigned short* attnE = (unsigned short*)(w + 84 * M1);
  float* rw      = w + 90 * M1;  // [2048,2]
  float* rattn   = w + 91 * M1;  // [2048,1024] f32
  float* routed  = w + 93 * M1;
  float* comp    = w + 95 * M1;  // [2048,256] f32
  float* expd    = w + 96 * M1;

  float* hFinal_out = out;
  float* hl_out     = out + 2 * M1;
  float* cn_out     = out + 4 * M1;

  const float scaleq = 0.08838834764831845f;  // 1/sqrt(128)
  const int ZBIG = 1 << 30;
  dim3 blk(256);
  const float* nf = nullptr;

  // gates = x@W_ih^T + h@W_hh^T + b_ih + b_hh
  gemm_k<128, 1, 1, 0, 0, 0><<<dim3(32, 16, 1), blk, 0, stream>>>(
      x, nullptr, 1024, 0, h, 1024, 1024,
      W_ih, nf, 1024, 0, W_hh, 1024,
      b_ih, nf, 0, b_hh,
      gates, nullptr, 4096, 0,
      2048, ZBIG, 1.f, nf, nf, nf, nf);

  transpose_k<<<dim3(16, 16, 2), blk, 0, stream>>>(sWk, wkTs, cWk, wkTc, 1024);

  lstm_k<<<2048, blk, 0, stream>>>(gates, c, Wrout, brout, cn_out, hl, hl_out, rw);

  // qs (z=0 self, z=1 ext), scaled, bf16 out
  gemm_k<128, 0, 0, 0, 0, 1><<<dim3(8, 16, 2), blk, 0, stream>>>(
      hl, hl, 1024, 0, nullptr, 0, 0,
      sWq, cWq, 1024, 0, nf, 0,
      sbq, cbq, 0, nf,
      qsS, qsE, 1024, 0,
      1024, 1, scaleq, nf, nf, nf, nf);

  // qt[b,h,k] = sum_d qs[b,h*128+d]*WkT[k,h*128+d]; z: 0-7 self, 8-15 ext
  gemm_k<128, 0, 0, 0, 1, 1><<<dim3(8, 16, 16), blk, 0, stream>>>(
      qsS, qsE, 1024, 128, nullptr, 0, 0,
      wkTs, wkTc, 1024, 128, nf, 0,
      nf, nf, 0, nf,
      qtS, qtE, 8192, 1024,
      128, 8, 1.f, nf, nf, nf, nf);

  // attention: partial scores -> softmax -> V mix (massively parallel)
  scores_k<<<dim3(2048, 2, 8), blk, 0, stream>>>(memK, extK, hl, qtS, qtE, pS, ts);
  softmax_k<<<dim3(2048, 2), blk, 0, stream>>>(pS, Pbuf);
  mix_k<<<dim3(2048, 2, 8), blk, 0, stream>>>(memV, extV, hl, Pbuf, mixS, mixE);

  // attn'[b,h*128+d] = (mix@Wv_h^T + bv) * rw ; z: 0-7 self, 8-15 ext; bf16
  gemm_k<64, 0, 0, 3, 1, 1><<<dim3(2, 16, 16), blk, 0, stream>>>(
      mixS, mixE, 8192, 1024, nullptr, 0, 0,
      sWv, cWv, 1024, 131072, nf, 0,
      sbv, cbv, 128, nf,
      attnS, attnE, 1024, 128,
      1024, 8, 1.f, rw, nf, nf, nf);

  // rattn = [w0*attnS | w1*attnE] @ [sWo;cWo]^T + w0*sbo + w1*cbo
  gemm_k<64, 1, 1, 4, 1, 0><<<dim3(16, 16, 1), blk, 0, stream>>>(
      attnS, nullptr, 1024, 0, attnE, 1024, 1024,
      sWo, nf, 1024, 0, cWo, 1024,
      nf, nf, 0, nf,
      rattn, nullptr, 1024, 0,
      2048, ZBIG, 1.f, sbo, cbo, rw, nf);

  // routed = h_lstm + rattn + rattn@Wres^T + bres
  gemm_k<64, 0, 0, 1, 0, 0><<<dim3(16, 16, 1), blk, 0, stream>>>(
      rattn, nullptr, 1024, 0, nullptr, 0, 0,
      Wres, nf, 1024, 0, nf, 0,
      bres, nf, 0, nf,
      routed, nullptr, 1024, 0,
      1024, ZBIG, 1.f, hl, rattn, nf, nf);

  // compressed / expanded
  gemm_k<64, 0, 0, 0, 0, 0><<<dim3(4, 16, 1), blk, 0, stream>>>(
      ts, nullptr, 1024, 0, nullptr, 0, 0,
      Wcomp, nf, 1024, 0, nf, 0,
      bcomp, nf, 0, nf,
      comp, nullptr, 256, 0,
      1024, ZBIG, 1.f, nf, nf, nf, nf);
  gemm_k<64, 0, 0, 0, 0, 0><<<dim3(16, 16, 1), blk, 0, stream>>>(
      comp, nullptr, 256, 0, nullptr, 0, 0,
      Wexp, nf, 256, 0, nf, 0,
      bexp, nf, 0, nf,
      expd, nullptr, 1024, 0,
      256, ZBIG, 1.f, nf, nf, nf, nf);

  // gate GEMM (A = [x | routed]) + fused final epilogue
  gemm_k<64, 1, 0, 2, 0, 0><<<dim3(16, 16, 1), blk, 0, stream>>>(
      x, nullptr, 1024, 0, routed, 1024, 1024,
      Wgate, nf, 2048, 0, nf, 0,
      bgate, nf, 0, nf,
      hFinal_out, nullptr, 1024, 0,
      2048, ZBIG, 1.f, comp, expd, hl, routed);
}

// Round 6
// 792.453 us; speedup vs baseline: 1.1076x; 1.1076x over previous
//
#include <hip/hip_runtime.h>
#include <math.h>

typedef __attribute__((ext_vector_type(4))) float f32x4;
typedef __attribute__((ext_vector_type(8))) short bf16x8;
typedef __attribute__((ext_vector_type(4))) unsigned short u16x4;

__device__ __forceinline__ unsigned short f2bf(float f) {
  unsigned u = __builtin_bit_cast(unsigned, f);
  u += 0x7fffu + ((u >> 16) & 1u);
  return (unsigned short)(u >> 16);
}
__device__ __forceinline__ float bf2f(unsigned short s) {
  return __builtin_bit_cast(float, (unsigned)s << 16);
}
__device__ __forceinline__ float sigmoidf_(float x) { return 1.f / (1.f + __expf(-x)); }

// ---------------------------------------------------------------------------
// bf16-MFMA GEMM, 128xTN tile (TN=128 or 64), BK=32, 4 waves, double-buffered
// LDS + 1-deep register prefetch, bijective XCD swizzle (grid product %8==0).
// C[M,N] = A[M,K] @ B[N,K]^T (+bias).
// ACAT/BCAT: K-concat (1st ptr k<Ksplit, 2nd after). z-split: z>=zs -> "b" set.
// ABF16: A is bf16. OBF16: C bf16 (EPI 0/3).
// EPI 0: (val)*scale
// EPI 1: val + P0[off] + P1[off]
// EPI 2: (P2+P3+ce+sig(val)*(P1-ce))/3, ce=P0[row*256+(col&255)]
// EPI 3: val * P0[2*row+hi]                       (rw-scaled, bf16 out)
// EPI 4: val + P2[2*row]*P0[col] + P2[2*row+1]*P1[col]
// ---------------------------------------------------------------------------
template <int TN, int ACAT, int BCAT, int EPI, int ABF16, int OBF16>
__global__ __launch_bounds__(256) void gemm_k(
    const void* __restrict__ A1, const void* __restrict__ A1b, int lda1, long aZ,
    const void* __restrict__ A2, int lda2, int Ksplit,
    const float* __restrict__ B1, const float* __restrict__ B1b, int ldb1, long bZ,
    const float* __restrict__ B2, int ldb2,
    const float* __restrict__ bias1, const float* __restrict__ bias1b, long biasZ,
    const float* __restrict__ bias2,
    void* __restrict__ C, void* __restrict__ Cb, int ldc, long cZ,
    int K, int zs, float scale,
    const float* __restrict__ P0, const float* __restrict__ P1,
    const float* __restrict__ P2, const float* __restrict__ P3) {
  constexpr int NBI = TN / 32;
  __shared__ unsigned short As[2][128][32];
  __shared__ unsigned short Bs[2][TN][32];
  const int t = threadIdx.x;
  const int lane = t & 63;
  const int wave = t >> 6;
  const int wr = wave >> 1, wc = wave & 1;

  const unsigned gx = gridDim.x, gy = gridDim.y;
  unsigned L = blockIdx.x + gx * (blockIdx.y + gy * blockIdx.z);
  const unsigned nwg = gx * gy * gridDim.z;
  L = (L & 7u) * (nwg >> 3) + (L >> 3);
  const int bn = L % gx;
  const unsigned r1 = L / gx;
  const int bm = r1 % gy;
  const int z = r1 / gy;

  const bool hi = z >= zs;
  const int zz = hi ? z - zs : z;
  const char* Abase = (const char*)(hi ? A1b : A1) + (long)zz * aZ * (ABF16 ? 2 : 4);
  const float* Bbase = (hi ? B1b : B1) + (long)zz * bZ;
  const float* biasp = hi ? bias1b : bias1;
  char* Czc = (char*)(hi ? Cb : C) + (long)zz * cZ * (OBF16 ? 2 : 4);

  const int ar = t >> 3;
  const int bc = (t & 7) * 4;

  const int kIters = K >> 5;
  u16x4 Ra[4], Rb[NBI];

  auto loadT = [&](int kt) {
    const int k0 = kt << 5;
    const char* Ap; int ldA, kA;
    if (ACAT == 1 && k0 >= Ksplit) { Ap = (const char*)A2; ldA = lda2; kA = k0 - Ksplit; }
    else { Ap = Abase; ldA = lda1; kA = k0; }
    const float* Bp; int ldB, kB;
    if (BCAT == 1 && k0 >= Ksplit) { Bp = B2; ldB = ldb2; kB = k0 - Ksplit; }
    else { Bp = Bbase; ldB = ldb1; kB = k0; }
#pragma unroll
    for (int i = 0; i < 4; ++i) {
      const long aoff = ((long)bm * 128 + ar + 32 * i) * ldA + kA + bc;
      if (ABF16) {
        Ra[i] = *(const u16x4*)((const unsigned short*)Ap + aoff);
      } else {
        f32x4 v = *(const f32x4*)((const float*)Ap + aoff);
        u16x4 pk;
        pk[0] = f2bf(v[0]); pk[1] = f2bf(v[1]); pk[2] = f2bf(v[2]); pk[3] = f2bf(v[3]);
        Ra[i] = pk;
      }
    }
#pragma unroll
    for (int i = 0; i < NBI; ++i) {
      f32x4 bv = *(const f32x4*)(Bp + ((long)bn * TN + ar + 32 * i) * ldB + kB + bc);
      u16x4 bp;
      bp[0] = f2bf(bv[0]); bp[1] = f2bf(bv[1]); bp[2] = f2bf(bv[2]); bp[3] = f2bf(bv[3]);
      Rb[i] = bp;
    }
  };

  loadT(0);

  f32x4 acc[4][NBI] = {};
  int p = 0;
  for (int kt = 0; kt < kIters; ++kt) {
    __syncthreads();
#pragma unroll
    for (int i = 0; i < 4; ++i) *(u16x4*)&As[p][ar + 32 * i][bc] = Ra[i];
#pragma unroll
    for (int i = 0; i < NBI; ++i) *(u16x4*)&Bs[p][ar + 32 * i][bc] = Rb[i];
    if (kt + 1 < kIters) loadT(kt + 1);
    __syncthreads();

    bf16x8 af[4], bfr[NBI];
#pragma unroll
    for (int mi = 0; mi < 4; ++mi)
      af[mi] = *(const bf16x8*)&As[p][wr * 64 + mi * 16 + (lane & 15)][(lane >> 4) * 8];
#pragma unroll
    for (int ni = 0; ni < NBI; ++ni)
      bfr[ni] = *(const bf16x8*)&Bs[p][wc * (TN / 2) + ni * 16 + (lane & 15)][(lane >> 4) * 8];
#pragma unroll
    for (int mi = 0; mi < 4; ++mi)
#pragma unroll
      for (int ni = 0; ni < NBI; ++ni)
        acc[mi][ni] = __builtin_amdgcn_mfma_f32_16x16x32_bf16(af[mi], bfr[ni], acc[mi][ni], 0, 0, 0);
    p ^= 1;
  }

  const int colb = bn * TN + wc * (TN / 2);
  const int rowb = bm * 128 + wr * 64;
#pragma unroll
  for (int mi = 0; mi < 4; ++mi) {
#pragma unroll
    for (int ni = 0; ni < NBI; ++ni) {
      f32x4 v = acc[mi][ni];
      const int col = colb + ni * 16 + (lane & 15);
      const int row0 = rowb + mi * 16 + ((lane >> 4) << 2);
      float bsum = 0.f;
      if (biasp) bsum += biasp[zz * biasZ + col];
      if (bias2) bsum += bias2[col];
#pragma unroll
      for (int q = 0; q < 4; ++q) {
        const long row = row0 + q;
        const long off = row * ldc + col;
        const float val = v[q] + bsum;
        if (EPI == 0) {
          if (OBF16) ((unsigned short*)Czc)[off] = f2bf(val * scale);
          else       ((float*)Czc)[off] = val * scale;
        } else if (EPI == 1) {
          ((float*)Czc)[off] = val + P0[off] + P1[off];
        } else if (EPI == 2) {
          const float g = sigmoidf_(val);
          const float ce = P0[row * 256 + (col & 255)];
          const float ex = P1[off];
          ((float*)Czc)[off] = (P2[off] + P3[off] + ce + g * (ex - ce)) * (1.f / 3.f);
        } else if (EPI == 3) {
          ((unsigned short*)Czc)[off] = f2bf(val * P0[2 * row + (hi ? 1 : 0)]);
        } else {
          ((float*)Czc)[off] = val + P2[2 * row] * P0[col] + P2[2 * row + 1] * P1[col];
        }
      }
    }
  }
}

// 64x64 LDS-tiled transpose, z selects (in,out) pair. out[n][d] = in[d][n]
__global__ __launch_bounds__(256) void transpose_k(const float* __restrict__ in0,
                                                   float* __restrict__ out0,
                                                   const float* __restrict__ in1,
                                                   float* __restrict__ out1, int n) {
  __shared__ float tile[64][65];
  const float* in = blockIdx.z ? in1 : in0;
  float* out = blockIdx.z ? out1 : out0;
  const int tr = blockIdx.y, tc = blockIdx.x, t = threadIdx.x;
#pragma unroll
  for (int it = 0; it < 16; ++it) {
    int idx = t + 256 * it;
    int r = idx >> 6, c = idx & 63;
    tile[r][c] = in[(long)(tr * 64 + r) * n + tc * 64 + c];
  }
  __syncthreads();
#pragma unroll
  for (int it = 0; it < 16; ++it) {
    int idx = t + 256 * it;
    int rr = idx >> 6, cc = idx & 63;
    out[(long)(tc * 64 + rr) * n + tr * 64 + cc] = tile[cc][rr];
  }
}

// LSTM elementwise + fused router (block == one batch row b)
__global__ __launch_bounds__(256) void lstm_k(const float* __restrict__ gates,
                                              const float* __restrict__ c_in,
                                              const float* __restrict__ Wr,
                                              const float* __restrict__ br,
                                              float* __restrict__ c_out,
                                              float* __restrict__ h_ws,
                                              float* __restrict__ h_out,
                                              float* __restrict__ rw) {
  const int b = blockIdx.x, t = threadIdx.x;
  const long base = (long)b * 1024 + t * 4;
  const float* gb = gates + (long)b * 4096 + t * 4;
  f32x4 gi = *(const f32x4*)(gb);
  f32x4 gf = *(const f32x4*)(gb + 1024);
  f32x4 gg = *(const f32x4*)(gb + 2048);
  f32x4 go = *(const f32x4*)(gb + 3072);
  f32x4 cv = *(const f32x4*)(c_in + base);
  f32x4 cn, hv;
#pragma unroll
  for (int q = 0; q < 4; ++q) {
    float cc = sigmoidf_(gf[q]) * cv[q] + sigmoidf_(gi[q]) * tanhf(gg[q]);
    cn[q] = cc;
    hv[q] = sigmoidf_(go[q]) * tanhf(cc);
  }
  *(f32x4*)(c_out + base) = cn;
  *(f32x4*)(h_ws + base) = hv;
  *(f32x4*)(h_out + base) = hv;
  f32x4 w0 = *(const f32x4*)(Wr + t * 4);
  f32x4 w1 = *(const f32x4*)(Wr + 1024 + t * 4);
  float a0 = hv[0] * w0[0] + hv[1] * w0[1] + hv[2] * w0[2] + hv[3] * w0[3];
  float a1 = hv[0] * w1[0] + hv[1] * w1[1] + hv[2] * w1[2] + hv[3] * w1[3];
#pragma unroll
  for (int m = 32; m >= 1; m >>= 1) {
    a0 += __shfl_xor(a0, m);
    a1 += __shfl_xor(a1, m);
  }
  __shared__ float red[8];
  if ((t & 63) == 0) { red[t >> 6] = a0; red[4 + (t >> 6)] = a1; }
  __syncthreads();
  if (t == 0) {
    float z0 = red[0] + red[1] + red[2] + red[3] + br[0];
    float z1 = red[4] + red[5] + red[6] + red[7] + br[1];
    float mx = fmaxf(z0, z1);
    float e0 = __expf(z0 - mx), e1 = __expf(z1 - mx);
    float s = e0 + e1;
    rw[2 * b] = e0 / s;
    rw[2 * b + 1] = e1 / s;
  }
}

// ---------------------------------------------------------------------------
// Fused attention (Lq=1), block = (b, side). FULL-ROW streaming: each of the
// 32 K rows (4 KB) is read contiguously by the whole block in one iteration
// (DRAM page-friendly), staged bf16 in LDS in MFMA-A subtile layout
// (32 jj-blocks of [32 rows][pitch 36], k=jj*32..). Scores: every wave
// redundantly accumulates the FULL score matrix (64 MFMAs) -> no cross-wave
// reduce. Softmax in-register per wave -> P_lds [16][36] bf16 (rows 8..15=0).
// V phase reuses the same LDS transposed ([1024 d][pitch 38], l consecutive),
// staged as row-pairs packed into dwords; 16 MFMAs produce mix.
// Self side also emits ts = column mean of K.
// ---------------------------------------------------------------------------
__global__ __launch_bounds__(256) void attn4_k(
    const float* __restrict__ memK, const float* __restrict__ memV,
    const float* __restrict__ extK, const float* __restrict__ extV,
    const float* __restrict__ hl,
    const unsigned short* __restrict__ qtS, const unsigned short* __restrict__ qtE,
    unsigned short* __restrict__ mixS, unsigned short* __restrict__ mixE,
    float* __restrict__ ts) {
  const int NB = 2048, H = 1024;
  __shared__ __align__(16) unsigned short LDSU[38912];  // K: 32*1168; V: 1024*38
  __shared__ __align__(16) unsigned short P_lds[16 * 36];
  const int b = blockIdx.x;
  const bool self = blockIdx.y == 0;
  const int t = threadIdx.x, lane = t & 63, w = t >> 6;

  auto krow = [&](int r) -> const float* {
    return self ? ((r < 31) ? memK + ((long)(r + 1) * NB + b) * H : hl + (long)b * H)
                : extK + ((long)r * NB + b) * H;
  };
  auto vrow = [&](int r) -> const float* {
    return self ? ((r < 31) ? memV + ((long)(r + 1) * NB + b) * H : hl + (long)b * H)
                : extV + ((long)r * NB + b) * H;
  };

  // ================= K staging: one full contiguous 4KB row per iteration ===
  // thread t covers chunk t (cols t*4..t*4+3); LDS dest: jj = ch*4 + (c4>>3)
  const int chS = t >> 5, c4S = t & 31;
  const unsigned kbase = (unsigned)(chS * 4 + (c4S >> 3)) * 1168 + (unsigned)(c4S & 7) * 4;
#pragma unroll
  for (int g = 0; g < 4; ++g) {
    f32x4 R[8];
#pragma unroll
    for (int u = 0; u < 8; ++u) R[u] = *(const f32x4*)(krow(g * 8 + u) + t * 4);
#pragma unroll
    for (int u = 0; u < 8; ++u) {
      const int r = g * 8 + u;
      u16x4 pk;
      pk[0] = f2bf(R[u][0]); pk[1] = f2bf(R[u][1]); pk[2] = f2bf(R[u][2]); pk[3] = f2bf(R[u][3]);
      *(u16x4*)&LDSU[kbase + (unsigned)r * 36] = pk;
    }
  }
  __syncthreads();

  // ---- ts (self): column means ----
  if (self) {
#pragma unroll
    for (int ci = 0; ci < 4; ++ci) {
      const int g = t + 256 * ci;
      const int q = g & 127;
      const unsigned short* base = &LDSU[(unsigned)((g >> 7) * 4 + (q >> 5)) * 1168 + (q & 31)];
      float s = 0.f;
#pragma unroll
      for (int r = 0; r < 32; ++r) s += bf2f(base[r * 36]);
      ts[(long)b * H + g] = s * (1.f / 32.f);
    }
  }

  // ================= scores: full accumulation per wave (redundant x4) ======
  const unsigned short* qtb =
      (self ? qtS : qtE) + (long)b * 8192 + (long)(lane & 7) * 1024 + (lane >> 4) * 8;
  f32x4 accS[2] = {};
  for (int jj = 0; jj < 32; ++jj) {
    bf16x8 bq = *(const bf16x8*)(qtb + jj * 32);
#pragma unroll
    for (int mi = 0; mi < 2; ++mi) {
      const unsigned short* ap =
          &LDSU[(unsigned)jj * 1168 + (unsigned)(mi * 16 + (lane & 15)) * 36 + (lane >> 4) * 8];
      union { unsigned long long q[2]; bf16x8 v; } ua;
      ua.q[0] = *(const unsigned long long*)ap;
      ua.q[1] = *(const unsigned long long*)(ap + 4);
      accS[mi] = __builtin_amdgcn_mfma_f32_16x16x32_bf16(ua.v, bq, accS[mi], 0, 0, 0);
    }
  }

  // ---- softmax per wave (lane&15 = head col; rows l = mi*16+(lane>>4)*4+q) --
  {
    float mx = -3.4e38f;
#pragma unroll
    for (int mi = 0; mi < 2; ++mi)
#pragma unroll
      for (int q = 0; q < 4; ++q) mx = fmaxf(mx, accS[mi][q]);
    mx = fmaxf(mx, __shfl_xor(mx, 16));
    mx = fmaxf(mx, __shfl_xor(mx, 32));
    float sum = 0.f;
    float pv[2][4];
#pragma unroll
    for (int mi = 0; mi < 2; ++mi)
#pragma unroll
      for (int q = 0; q < 4; ++q) { pv[mi][q] = __expf(accS[mi][q] - mx); sum += pv[mi][q]; }
    sum += __shfl_xor(sum, 16);
    sum += __shfl_xor(sum, 32);
    const float rinv = 1.f / sum;
    const bool valid = (lane & 15) < 8;
#pragma unroll
    for (int mi = 0; mi < 2; ++mi) {
      u16x4 pk;
#pragma unroll
      for (int q = 0; q < 4; ++q) pk[q] = valid ? f2bf(pv[mi][q] * rinv) : (unsigned short)0;
      *(u16x4*)&P_lds[(unsigned)(lane & 15) * 36 + mi * 16 + (lane >> 4) * 4] = pk;
    }
  }
  __syncthreads();  // KT reads + ts done; P written -> safe to overwrite with V

  // ================= V staging: row-pairs, transposed [d][l] pitch 38 =======
#pragma unroll
  for (int g = 0; g < 4; ++g) {
    f32x4 RA[4], RB[4];
#pragma unroll
    for (int u = 0; u < 4; ++u) {
      const int pr = g * 4 + u;
      RA[u] = *(const f32x4*)(vrow(2 * pr) + t * 4);
      RB[u] = *(const f32x4*)(vrow(2 * pr + 1) + t * 4);
    }
#pragma unroll
    for (int u = 0; u < 4; ++u) {
      const int pr = g * 4 + u;
#pragma unroll
      for (int e = 0; e < 4; ++e) {
        const unsigned dw = (unsigned)f2bf(RA[u][e]) | ((unsigned)f2bf(RB[u][e]) << 16);
        *(unsigned*)&LDSU[(unsigned)(t * 4 + e) * 38 + 2 * pr] = dw;
      }
    }
  }
  __syncthreads();

  // ================= mix: P x V^T, 16 MFMAs per wave ========================
  bf16x8 pa = *(const bf16x8*)&P_lds[(unsigned)(lane & 15) * 36 + (lane >> 4) * 8];
  unsigned short* mixp = (self ? mixS : mixE) + (long)b * 8192;
#pragma unroll
  for (int ch = 0; ch < 8; ++ch) {
#pragma unroll
    for (int i = 0; i < 2; ++i) {
      const int dbase = ch * 128 + w * 32 + i * 16;
      const unsigned* vb =
          (const unsigned*)&LDSU[(unsigned)(dbase + (lane & 15)) * 38 + (lane >> 4) * 8];
      union { unsigned u[4]; bf16x8 v; } uu;
      uu.u[0] = vb[0]; uu.u[1] = vb[1]; uu.u[2] = vb[2]; uu.u[3] = vb[3];
      f32x4 o = __builtin_amdgcn_mfma_f32_16x16x32_bf16(pa, uu.v, (f32x4){0.f, 0.f, 0.f, 0.f},
                                                        0, 0, 0);
      if (lane < 32) {
        const int d = dbase + (lane & 15);
        const int h0 = (lane >> 4) * 4;
#pragma unroll
        for (int q = 0; q < 4; ++q) mixp[(long)(h0 + q) * 1024 + d] = f2bf(o[q]);
      }
    }
  }
}

extern "C" void kernel_launch(void* const* d_in, const int* in_sizes, int n_in,
                              void* d_out, int out_size, void* d_ws, size_t ws_size,
                              hipStream_t stream) {
  const float* x    = (const float*)d_in[0];
  const float* h    = (const float*)d_in[1];
  const float* c    = (const float*)d_in[2];
  const float* memK = (const float*)d_in[3];
  const float* memV = (const float*)d_in[4];
  const float* extK = (const float*)d_in[5];
  const float* extV = (const float*)d_in[6];
  const float* W_ih = (const float*)d_in[7];
  const float* W_hh = (const float*)d_in[8];
  const float* b_ih = (const float*)d_in[9];
  const float* b_hh = (const float*)d_in[10];
  const float* sWq = (const float*)d_in[11];
  const float* sbq = (const float*)d_in[12];
  const float* sWk = (const float*)d_in[13];
  const float* sWv = (const float*)d_in[15];
  const float* sbv = (const float*)d_in[16];
  const float* sWo = (const float*)d_in[17];
  const float* sbo = (const float*)d_in[18];
  const float* cWq = (const float*)d_in[19];
  const float* cbq = (const float*)d_in[20];
  const float* cWk = (const float*)d_in[21];
  const float* cWv = (const float*)d_in[23];
  const float* cbv = (const float*)d_in[24];
  const float* cWo = (const float*)d_in[25];
  const float* cbo = (const float*)d_in[26];
  const float* Wres = (const float*)d_in[27];
  const float* bres = (const float*)d_in[28];
  const float* Wrout = (const float*)d_in[29];
  const float* brout = (const float*)d_in[30];
  const float* Wcomp = (const float*)d_in[31];
  const float* bcomp = (const float*)d_in[32];
  const float* Wexp = (const float*)d_in[33];
  const float* bexp = (const float*)d_in[34];
  const float* Wgate = (const float*)d_in[35];
  const float* bgate = (const float*)d_in[36];
  (void)in_sizes; (void)n_in; (void)out_size; (void)ws_size;

  float* out = (float*)d_out;
  float* w = (float*)d_ws;
  const long M1 = 1024 * 1024;
  float* gates   = w;            // [2048,4096] f32 ; dead after lstm_k
  float* hl      = w + 8 * M1;   // [2048,1024] f32
  unsigned short* qsS = (unsigned short*)(w + 10 * M1);  // [2048,1024] bf16
  unsigned short* qsE = (unsigned short*)(w + 12 * M1);
  float* wkTs    = w + 14 * M1;  // [1024,1024] f32
  float* wkTc    = w + 15 * M1;
  unsigned short* qtS = (unsigned short*)(w + 16 * M1);  // [2048,8192] bf16
  unsigned short* qtE = (unsigned short*)(w + 32 * M1);
  unsigned short* mixS = (unsigned short*)(w + 48 * M1); // [2048,8192] bf16
  unsigned short* mixE = (unsigned short*)(w + 64 * M1);
  float* ts      = w + 80 * M1;  // [2048,1024] f32
  unsigned short* attnS = (unsigned short*)(w + 82 * M1);  // [2048,1024] bf16 (rw-scaled)
  unsigned short* attnE = (unsigned short*)(w + 84 * M1);
  float* rw      = w + 90 * M1;  // [2048,2]
  float* rattn   = w + 91 * M1;  // [2048,1024] f32
  float* routed  = w + 93 * M1;
  float* comp    = w + 95 * M1;  // [2048,256] f32
  float* expd    = w + 96 * M1;

  float* hFinal_out = out;
  float* hl_out     = out + 2 * M1;
  float* cn_out     = out + 4 * M1;

  const float scaleq = 0.08838834764831845f;  // 1/sqrt(128)
  const int ZBIG = 1 << 30;
  dim3 blk(256);
  const float* nf = nullptr;

  // gates = x@W_ih^T + h@W_hh^T + b_ih + b_hh
  gemm_k<128, 1, 1, 0, 0, 0><<<dim3(32, 16, 1), blk, 0, stream>>>(
      x, nullptr, 1024, 0, h, 1024, 1024,
      W_ih, nf, 1024, 0, W_hh, 1024,
      b_ih, nf, 0, b_hh,
      gates, nullptr, 4096, 0,
      2048, ZBIG, 1.f, nf, nf, nf, nf);

  transpose_k<<<dim3(16, 16, 2), blk, 0, stream>>>(sWk, wkTs, cWk, wkTc, 1024);

  lstm_k<<<2048, blk, 0, stream>>>(gates, c, Wrout, brout, cn_out, hl, hl_out, rw);

  // qs (z=0 self, z=1 ext), scaled, bf16 out
  gemm_k<128, 0, 0, 0, 0, 1><<<dim3(8, 16, 2), blk, 0, stream>>>(
      hl, hl, 1024, 0, nullptr, 0, 0,
      sWq, cWq, 1024, 0, nf, 0,
      sbq, cbq, 0, nf,
      qsS, qsE, 1024, 0,
      1024, 1, scaleq, nf, nf, nf, nf);

  // qt[b,h,k] = sum_d qs[b,h*128+d]*WkT[k,h*128+d]; z: 0-7 self, 8-15 ext
  gemm_k<128, 0, 0, 0, 1, 1><<<dim3(8, 16, 16), blk, 0, stream>>>(
      qsS, qsE, 1024, 128, nullptr, 0, 0,
      wkTs, wkTc, 1024, 128, nf, 0,
      nf, nf, 0, nf,
      qtS, qtE, 8192, 1024,
      128, 8, 1.f, nf, nf, nf, nf);

  // fused attention: full-row streaming, scores+softmax+mix in one kernel
  attn4_k<<<dim3(2048, 2), blk, 0, stream>>>(memK, memV, extK, extV, hl,
                                             qtS, qtE, mixS, mixE, ts);

  // attn'[b,h*128+d] = (mix@Wv_h^T + bv) * rw ; z: 0-7 self, 8-15 ext; bf16
  gemm_k<64, 0, 0, 3, 1, 1><<<dim3(2, 16, 16), blk, 0, stream>>>(
      mixS, mixE, 8192, 1024, nullptr, 0, 0,
      sWv, cWv, 1024, 131072, nf, 0,
      sbv, cbv, 128, nf,
      attnS, attnE, 1024, 128,
      1024, 8, 1.f, rw, nf, nf, nf);

  // rattn = [w0*attnS | w1*attnE] @ [sWo;cWo]^T + w0*sbo + w1*cbo
  gemm_k<64, 1, 1, 4, 1, 0><<<dim3(16, 16, 1), blk, 0, stream>>>(
      attnS, nullptr, 1024, 0, attnE, 1024, 1024,
      sWo, nf, 1024, 0, cWo, 1024,
      nf, nf, 0, nf,
      rattn, nullptr, 1024, 0,
      2048, ZBIG, 1.f, sbo, cbo, rw, nf);

  // routed = h_lstm + rattn + rattn@Wres^T + bres
  gemm_k<64, 0, 0, 1, 0, 0><<<dim3(16, 16, 1), blk, 0, stream>>>(
      rattn, nullptr, 1024, 0, nullptr, 0, 0,
      Wres, nf, 1024, 0, nf, 0,
      bres, nf, 0, nf,
      routed, nullptr, 1024, 0,
      1024, ZBIG, 1.f, hl, rattn, nf, nf);

  // compressed / expanded
  gemm_k<64, 0, 0, 0, 0, 0><<<dim3(4, 16, 1), blk, 0, stream>>>(
      ts, nullptr, 1024, 0, nullptr, 0, 0,
      Wcomp, nf, 1024, 0, nf, 0,
      bcomp, nf, 0, nf,
      comp, nullptr, 256, 0,
      1024, ZBIG, 1.f, nf, nf, nf, nf);
  gemm_k<64, 0, 0, 0, 0, 0><<<dim3(16, 16, 1), blk, 0, stream>>>(
      comp, nullptr, 256, 0, nullptr, 0, 0,
      Wexp, nf, 256, 0, nf, 0,
      bexp, nf, 0, nf,
      expd, nullptr, 1024, 0,
      256, ZBIG, 1.f, nf, nf, nf, nf);

  // gate GEMM (A = [x | routed]) + fused final epilogue
  gemm_k<64, 1, 0, 2, 0, 0><<<dim3(16, 16, 1), blk, 0, stream>>>(
      x, nullptr, 1024, 0, routed, 1024, 1024,
      Wgate, nf, 2048, 0, nf, 0,
      bgate, nf, 0, nf,
      hFinal_out, nullptr, 1024, 0,
      2048, ZBIG, 1.f, comp, expd, hl, routed);
}